// Round 1
// baseline (1601.939 us; speedup 1.0000x reference)
//
#include <hip/hip_runtime.h>

// Problem constants
// x: (16, 64, 256, 256) f32 ; z: (16, 64, 32, 32) f32 ; freq_coeff: (8,5,2) f32
// out: (16, 16, 125, 125) f32
static constexpr int OHW = 125;

// ---------------------------------------------------------------------------
// Kernel 1: build the 64x64 linear filter matrix Mt from freq_coeff.
// w_new = Re( (1/64) * sum_{p,q in 0..7} Ghat[p,q] e^{i2pi(p*x+q*y)/8} )
// Ghat[p,q] = f_new[p,q] for q<=4 ; Ghat[p,q] = conj(f_new[(8-p)%8, 8-q]) q>=5
// For impulse at (u,v): Re f = cos(th)/8, Im f = -sin(th)/8, th=2pi(pu+qv)/8
// f_new = a*Re f + i*b*Im f.  Stored transposed: Mt[uv*64 + xy].
__global__ __launch_bounds__(256) void fft_mat_kernel(
    const float* __restrict__ fc, float* __restrict__ Mt) {
  int e = blockIdx.x * 256 + threadIdx.x;  // 0..4095
  int uv = e >> 6, xy = e & 63;
  int u = uv >> 3, v = uv & 7, xx = xy >> 3, yy = xy & 7;
  const float R2 = 0.70710678118654752f;
  const float ct[8] = {1.f, R2, 0.f, -R2, -1.f, -R2, 0.f, R2};
  const float st[8] = {0.f, R2, 1.f, R2, 0.f, -R2, -1.f, -R2};
  float sumv = 0.f;
  #pragma unroll
  for (int p = 0; p < 8; ++p) {
    #pragma unroll
    for (int q = 0; q < 8; ++q) {
      float Re, Im;
      if (q <= 4) {
        int th = (p * u + q * v) & 7;
        float a = fc[(p * 5 + q) * 2 + 0];
        float b = fc[(p * 5 + q) * 2 + 1];
        Re = a * ct[th];
        Im = -b * st[th];
      } else {
        int pp = (8 - p) & 7, qq = 8 - q;
        int th = (pp * u + qq * v) & 7;
        float a = fc[(pp * 5 + qq) * 2 + 0];
        float b = fc[(pp * 5 + qq) * 2 + 1];
        Re = a * ct[th];
        Im = b * st[th];   // conjugated
      }
      int ph = (p * xx + q * yy) & 7;
      sumv += Re * ct[ph] - Im * st[ph];
    }
  }
  Mt[e] = sumv * (1.0f / 64.0f);
}

// ---------------------------------------------------------------------------
// Kernel 2: apply filter to z blocks -> W[(G*64+c)*64 + (kh*8+kw)]
// G = b*16 + n1*4 + n2 ; block handles one (G, quarter of c)
__global__ __launch_bounds__(256) void weight_kernel(
    const float* __restrict__ z, const float* __restrict__ Mt,
    float* __restrict__ W) {
  int blk = blockIdx.x;              // 1024 = G*4 + cq
  int G = blk >> 2, cq = blk & 3;
  int b = G >> 4, n1 = (G >> 2) & 3, n2 = G & 3;
  int tid = threadIdx.x;
  int cs = tid >> 6, xy = tid & 63;
  __shared__ float Ms[4096];
  __shared__ float zb[4][64];
  for (int i = tid; i < 4096; i += 256) Ms[i] = Mt[i];
  for (int it = 0; it < 4; ++it) {
    int c = cq * 16 + cs * 4 + it;
    __syncthreads();
    int u = xy >> 3, vv = xy & 7;
    zb[cs][xy] = z[(size_t)(b * 64 + c) * 1024 + (n1 * 8 + u) * 32 + (n2 * 8 + vv)];
    __syncthreads();
    float acc = 0.f;
    #pragma unroll
    for (int i = 0; i < 64; ++i) acc += Ms[i * 64 + xy] * zb[cs][i];
    W[((size_t)G * 64 + c) * 64 + xy] = acc;
  }
}

// ---------------------------------------------------------------------------
// Kernel 3: S[g][h][w] = sum_c x[g*64+c][h][w]^2 ; also zero the reduction acc
__global__ __launch_bounds__(256) void sq_sum_kernel(
    const float* __restrict__ x, float* __restrict__ S, double* __restrict__ red) {
  if (blockIdx.x == 0 && threadIdx.x < 2) red[threadIdx.x] = 0.0;
  int idx = blockIdx.x * 256 + threadIdx.x;  // 16*65536
  int g = idx >> 16, hw = idx & 65535;
  const float* xp = x + (size_t)g * 64 * 65536 + hw;
  float s = 0.f;
  #pragma unroll 8
  for (int c = 0; c < 64; ++c) {
    float v = xp[(size_t)c * 65536];
    s += v * v;
  }
  S[idx] = s;
}

// ---------------------------------------------------------------------------
// Kernel 4: plane[g][i][j] = 8x8 stride-2 box over S ; reduce sum/sumsq (f64)
__global__ __launch_bounds__(256) void box_kernel(
    const float* __restrict__ S, float* __restrict__ plane, double* __restrict__ red) {
  int idx = blockIdx.x * 256 + threadIdx.x;
  double v = 0.0, v2 = 0.0;
  if (idx < 16 * OHW * OHW) {
    int g = idx / (OHW * OHW);
    int rem = idx - g * (OHW * OHW);
    int i = rem / OHW, j = rem - (rem / OHW) * OHW;
    const float* Sp = S + (size_t)g * 65536 + (2 * i) * 256 + 2 * j;
    float s = 0.f;
    #pragma unroll
    for (int r = 0; r < 8; ++r)
      #pragma unroll
      for (int cc = 0; cc < 8; ++cc) s += Sp[r * 256 + cc];
    plane[idx] = s;
    v = (double)s;
    v2 = (double)s * (double)s;
  }
  #pragma unroll
  for (int off = 32; off > 0; off >>= 1) {
    v += __shfl_down(v, off);
    v2 += __shfl_down(v2, off);
  }
  __shared__ double sv[4], sv2[4];
  int wid = threadIdx.x >> 6, lane = threadIdx.x & 63;
  if (lane == 0) { sv[wid] = v; sv2[wid] = v2; }
  __syncthreads();
  if (threadIdx.x == 0) {
    atomicAdd(&red[0], sv[0] + sv[1] + sv[2] + sv[3]);
    atomicAdd(&red[1], sv2[0] + sv2[1] + sv2[2] + sv2[3]);
  }
}

// ---------------------------------------------------------------------------
// Kernel 5: shift = std(norm_full, ddof=1)/10 + 1e-9 over the x16-replicated
// tensor (n = 256*125*125); distinct sums were accumulated.
__global__ void finalize_kernel(const double* __restrict__ red, float* __restrict__ shiftp) {
  double sum = red[0], sumsq = red[1];
  double n = 256.0 * OHW * OHW;              // 4,000,000
  double mu = 16.0 * sum / n;
  double var = (16.0 * sumsq - n * mu * mu) / (n - 1.0);
  *shiftp = (float)(sqrt(var) / 10.0 + 1e-9);
}

// ---------------------------------------------------------------------------
// Kernel 6: grouped conv (stride 2, 8x8, VALID) + scaling.
// Tile: 16 cols x 8 rows of output, all 16 oc. 256 thr = 16 oc x 16 cols.
#define TW 16
#define TH 8
__global__ __launch_bounds__(256) void conv_scale_kernel(
    const float* __restrict__ x, const float* __restrict__ W,
    const float* __restrict__ plane, const float* __restrict__ shiftp,
    float* __restrict__ out) {
  int g = blockIdx.z;
  int j0 = blockIdx.x * TW;
  int i0 = blockIdx.y * TH;
  int tid = threadIdx.x;
  int oc = tid >> 4, cl = tid & 15;
  __shared__ float xt[22 * 40];   // 22 rows x 38 cols (pad to 40)
  __shared__ float wt[16 * 64];
  float acc[TH];
  #pragma unroll
  for (int i = 0; i < TH; ++i) acc[i] = 0.f;
  const float* xg = x + (size_t)g * 64 * 65536;
  const float* Wg = W + (size_t)g * 16 * 64 * 64;

  for (int c = 0; c < 64; ++c) {
    __syncthreads();
    for (int idx = tid; idx < 22 * 38; idx += 256) {
      int r = idx / 38, cc = idx - r * 38;
      int ri = 2 * i0 + r; if (ri > 255) ri = 255;
      int ci = 2 * j0 + cc; if (ci > 255) ci = 255;
      xt[r * 40 + cc] = xg[(size_t)c * 65536 + ri * 256 + ci];
    }
    for (int idx = tid; idx < 1024; idx += 256) {
      int o = idx >> 6, kk = idx & 63;
      wt[idx] = Wg[((size_t)o * 64 + c) * 64 + kk];
    }
    __syncthreads();

    float wreg[64];
    #pragma unroll
    for (int k = 0; k < 64; ++k) wreg[k] = wt[oc * 64 + k];

    #pragma unroll
    for (int r = 0; r < 22; ++r) {
      float xv[8];
      #pragma unroll
      for (int kw = 0; kw < 8; ++kw) xv[kw] = xt[r * 40 + 2 * cl + kw];
      #pragma unroll
      for (int py = 0; py < TH; ++py) {
        int kh = r - 2 * py;
        if (kh >= 0 && kh < 8) {
          float s = 0.f;
          #pragma unroll
          for (int kw = 0; kw < 8; ++kw) s += wreg[kh * 8 + kw] * xv[kw];
          acc[py] += s;
        }
      }
    }
  }

  float shift = *shiftp;
  int j = j0 + cl;
  if (j < OHW) {
    #pragma unroll
    for (int py = 0; py < TH; ++py) {
      int i = i0 + py;
      if (i < OHW) {
        float nrm = plane[(g * OHW + i) * OHW + j] + shift;
        out[(((size_t)g * 16 + oc) * OHW + i) * OHW + j] =
            acc[py] * 0.01f * rsqrtf(nrm);
      }
    }
  }
}

// ---------------------------------------------------------------------------
extern "C" void kernel_launch(void* const* d_in, const int* in_sizes, int n_in,
                              void* d_out, int out_size, void* d_ws, size_t ws_size,
                              hipStream_t stream) {
  const float* x  = (const float*)d_in[0];
  const float* z  = (const float*)d_in[1];
  const float* fc = (const float*)d_in[2];
  float* out = (float*)d_out;

  char* ws = (char*)d_ws;
  float*  W      = (float*)(ws);                     // 4 MB
  float*  Mt     = (float*)(ws + 4194304);           // 16 KB
  float*  S      = (float*)(ws + 4210688);           // 4 MB
  float*  plane  = (float*)(ws + 8404992);           // ~1 MB
  double* red    = (double*)(ws + 9404992);          // 16 B (8-aligned)
  float*  shiftp = (float*)(ws + 9405008);           // 4 B

  fft_mat_kernel<<<16, 256, 0, stream>>>(fc, Mt);
  weight_kernel<<<1024, 256, 0, stream>>>(z, Mt, W);
  sq_sum_kernel<<<(16 * 65536) / 256, 256, 0, stream>>>(x, S, red);
  box_kernel<<<(16 * OHW * OHW + 255) / 256, 256, 0, stream>>>(S, plane, red);
  finalize_kernel<<<1, 1, 0, stream>>>(red, shiftp);
  conv_scale_kernel<<<dim3(8, 16, 16), 256, 0, stream>>>(x, W, plane, shiftp, out);
}

// Round 2
// 722.413 us; speedup vs baseline: 2.2175x; 2.2175x over previous
//
#include <hip/hip_runtime.h>

typedef short short8 __attribute__((ext_vector_type(8)));
typedef float f32x4 __attribute__((ext_vector_type(4)));

static constexpr int OHW = 125;

__device__ inline unsigned int bf16_rne(float f) {
  unsigned int u = __float_as_uint(f);
  return (u + 0x7FFFu + ((u >> 16) & 1u)) >> 16;
}

// ---------------------------------------------------------------------------
// Kernel 1: build the 64x64 linear filter matrix Mt from freq_coeff.
__global__ __launch_bounds__(256) void fft_mat_kernel(
    const float* __restrict__ fc, float* __restrict__ Mt) {
  int e = blockIdx.x * 256 + threadIdx.x;  // 0..4095
  int uv = e >> 6, xy = e & 63;
  int u = uv >> 3, v = uv & 7, xx = xy >> 3, yy = xy & 7;
  const float R2 = 0.70710678118654752f;
  const float ct[8] = {1.f, R2, 0.f, -R2, -1.f, -R2, 0.f, R2};
  const float st[8] = {0.f, R2, 1.f, R2, 0.f, -R2, -1.f, -R2};
  float sumv = 0.f;
  #pragma unroll
  for (int p = 0; p < 8; ++p) {
    #pragma unroll
    for (int q = 0; q < 8; ++q) {
      float Re, Im;
      if (q <= 4) {
        int th = (p * u + q * v) & 7;
        float a = fc[(p * 5 + q) * 2 + 0];
        float b = fc[(p * 5 + q) * 2 + 1];
        Re = a * ct[th];
        Im = -b * st[th];
      } else {
        int pp = (8 - p) & 7, qq = 8 - q;
        int th = (pp * u + qq * v) & 7;
        float a = fc[(pp * 5 + qq) * 2 + 0];
        float b = fc[(pp * 5 + qq) * 2 + 1];
        Re = a * ct[th];
        Im = b * st[th];   // conjugated
      }
      int ph = (p * xx + q * yy) & 7;
      sumv += Re * ct[ph] - Im * st[ph];
    }
  }
  Mt[e] = sumv * (1.0f / 64.0f);
}

// ---------------------------------------------------------------------------
// Kernel 2: apply filter to z blocks -> bf16 Wp[g][c][kw][oc][kh]
__global__ __launch_bounds__(256) void weight_kernel(
    const float* __restrict__ z, const float* __restrict__ Mt,
    unsigned short* __restrict__ Wp) {
  int blk = blockIdx.x;              // 1024 = G*4 + cq
  int G = blk >> 2, cq = blk & 3;
  int b = G >> 4, n1 = (G >> 2) & 3, n2 = G & 3;
  int oc = G & 15;
  int tid = threadIdx.x;
  int cs = tid >> 6, xy = tid & 63;
  __shared__ float Ms[4096];
  __shared__ float zb[4][64];
  for (int i = tid; i < 4096; i += 256) Ms[i] = Mt[i];
  for (int it = 0; it < 4; ++it) {
    int c = cq * 16 + cs * 4 + it;
    __syncthreads();
    int u = xy >> 3, vv = xy & 7;
    zb[cs][xy] = z[(size_t)(b * 64 + c) * 1024 + (n1 * 8 + u) * 32 + (n2 * 8 + vv)];
    __syncthreads();
    float acc = 0.f;
    #pragma unroll
    for (int i = 0; i < 64; ++i) acc += Ms[i * 64 + xy] * zb[cs][i];
    int kh = xy >> 3, kw = xy & 7;
    Wp[(((size_t)(b * 64 + c) * 8 + kw) * 16 + oc) * 8 + kh] =
        (unsigned short)bf16_rne(acc);
  }
}

// ---------------------------------------------------------------------------
// Kernel 3: S[g][h][w] = sum_c x[g*64+c][h][w]^2 ; zero the reduction acc
__global__ __launch_bounds__(256) void sq_sum_kernel(
    const float* __restrict__ x, float* __restrict__ S, double* __restrict__ red) {
  if (blockIdx.x == 0 && threadIdx.x < 2) red[threadIdx.x] = 0.0;
  int idx = blockIdx.x * 256 + threadIdx.x;  // 16*65536
  int g = idx >> 16, hw = idx & 65535;
  const float* xp = x + (size_t)g * 64 * 65536 + hw;
  float s = 0.f;
  #pragma unroll 8
  for (int c = 0; c < 64; ++c) {
    float v = xp[(size_t)c * 65536];
    s += v * v;
  }
  S[idx] = s;
}

// ---------------------------------------------------------------------------
// Kernel 4: plane = 8x8 stride-2 box over S ; reduce sum/sumsq (f64)
__global__ __launch_bounds__(256) void box_kernel(
    const float* __restrict__ S, float* __restrict__ plane, double* __restrict__ red) {
  int idx = blockIdx.x * 256 + threadIdx.x;
  double v = 0.0, v2 = 0.0;
  if (idx < 16 * OHW * OHW) {
    int g = idx / (OHW * OHW);
    int rem = idx - g * (OHW * OHW);
    int i = rem / OHW, j = rem - (rem / OHW) * OHW;
    const float* Sp = S + (size_t)g * 65536 + (2 * i) * 256 + 2 * j;
    float s = 0.f;
    #pragma unroll
    for (int r = 0; r < 8; ++r)
      #pragma unroll
      for (int cc = 0; cc < 8; ++cc) s += Sp[r * 256 + cc];
    plane[idx] = s;
    v = (double)s;
    v2 = (double)s * (double)s;
  }
  #pragma unroll
  for (int off = 32; off > 0; off >>= 1) {
    v += __shfl_down(v, off);
    v2 += __shfl_down(v2, off);
  }
  __shared__ double sv[4], sv2[4];
  int wid = threadIdx.x >> 6, lane = threadIdx.x & 63;
  if (lane == 0) { sv[wid] = v; sv2[wid] = v2; }
  __syncthreads();
  if (threadIdx.x == 0) {
    atomicAdd(&red[0], sv[0] + sv[1] + sv[2] + sv[3]);
    atomicAdd(&red[1], sv2[0] + sv2[1] + sv2[2] + sv2[3]);
  }
}

// ---------------------------------------------------------------------------
// Kernel 5: shift = std(norm_full, ddof=1)/10 + 1e-9 (x16 replication folded)
__global__ void finalize_kernel(const double* __restrict__ red, float* __restrict__ shiftp) {
  double sum = red[0], sumsq = red[1];
  double n = 256.0 * OHW * OHW;
  double mu = 16.0 * sum / n;
  double var = (16.0 * sumsq - n * mu * mu) / (n - 1.0);
  *shiftp = (float)(sqrt(var) / 10.0 + 1e-9);
}

// ---------------------------------------------------------------------------
// Kernel 6: MFMA implicit-GEMM grouped conv + scaling.
// Block: g = blockIdx.y, 4 output rows i0..i0+3 (i0 = 4*blockIdx.x), all 125 j.
// 4 waves; wave ri computes row i0+ri for 8 tiles of 16 j via 16x16x32 bf16 MFMA.
// K order: (c, kw, kh). B frag = xs[ri][slot(col)][kh0..7] (column-major x tile).
// LDS: xs 4 rows x 297 slots x 8 kh bf16 (pitch 297 short8 = bank-staggered),
//      Wl 8 kw x (16 oc +1 pad) x 8 kh bf16 at uint offset 4752.
__global__ __launch_bounds__(256) void conv_mfma_kernel(
    const float* __restrict__ x, const unsigned short* __restrict__ Wp,
    const float* __restrict__ plane, const float* __restrict__ shiftp,
    float* __restrict__ out) {
  __shared__ __align__(16) unsigned int ldsbuf[5296];
  const int g = blockIdx.y, iblk = blockIdx.x;
  const int i0 = iblk * 4;
  const int tid = threadIdx.x;
  const int lane = tid & 63, ri = tid >> 6;
  const int q = lane >> 4, n = lane & 15;

  const float* xg = x + (size_t)g * 64 * 65536;
  const unsigned int* wg = (const unsigned int*)(Wp + (size_t)g * 65536);

  // Precompute staging items: 1848 = 7 row-pairs x 264 cols, rp-fastest.
  int nit = 0;
  int off0[8], off1[8], ubase[8], pcnt[8];
  for (int s = 0; s < 8; ++s) {
    int d = tid + (s << 8);
    if (d < 1848) {
      int rp = d % 7, col = d / 7;
      int r0 = 2 * i0 + 2 * rp;
      int r0c = min(r0, 255), r1c = min(r0 + 1, 255), cc = min(col, 255);
      off0[nit] = r0c * 256 + cc;
      off1[nit] = r1c * 256 + cc;
      int slot = col + (col >> 3);
      int pmin = rp - 3 > 0 ? rp - 3 : 0;
      int pmax = rp < 3 ? rp : 3;
      ubase[nit] = (rp - pmin) * 1188 + slot * 4 + pmin;  // uint index
      pcnt[nit] = pmax - pmin + 1;
      ++nit;
    }
  }

  f32x4 acc[8];
  #pragma unroll
  for (int t = 0; t < 8; ++t) acc[t] = (f32x4){0.f, 0.f, 0.f, 0.f};

  const short8* xsv = (const short8*)ldsbuf;
  const short8* wvv = ((const short8*)ldsbuf) + 1188;

  int bidx[2], aidx[2];
  #pragma unroll
  for (int h = 0; h < 2; ++h) {
    int kw = h * 4 + q;
    int col0 = 2 * n + kw;
    bidx[h] = ri * 297 + col0 + (col0 >> 3);
    aidx[h] = kw * 17 + n;   // n = lane&15 = oc (A's m)
  }

  for (int c = 0; c < 64; ++c) {
    __syncthreads();
    const float* xc = xg + (size_t)c * 65536;
    #pragma unroll
    for (int it = 0; it < 8; ++it) {
      if (it < nit) {
        float v0 = xc[off0[it]];
        float v1 = xc[off1[it]];
        unsigned int pk = bf16_rne(v0) | (bf16_rne(v1) << 16);
        int ub = ubase[it];
        for (int p = 0; p < pcnt[it]; ++p) {
          ldsbuf[ub] = pk;
          ub -= 1187;   // ri -= 1, kh-pair += 1
        }
      }
    }
    const unsigned int* wc = wg + c * 512;
    #pragma unroll
    for (int t2 = 0; t2 < 2; ++t2) {
      int t = tid + (t2 << 8);
      unsigned int wval = wc[t];
      ldsbuf[4752 + (t >> 6) * 68 + ((t >> 2) & 15) * 4 + (t & 3)] = wval;
    }
    __syncthreads();
    #pragma unroll
    for (int h = 0; h < 2; ++h) {
      short8 afrag = wvv[aidx[h]];
      int bb = bidx[h];
      #pragma unroll
      for (int T = 0; T < 8; ++T) {
        short8 bfrag = xsv[bb + T * 36];
        acc[T] = __builtin_amdgcn_mfma_f32_16x16x32_bf16(afrag, bfrag, acc[T], 0, 0, 0);
      }
    }
  }

  float shift = *shiftp;
  int i = i0 + ri;
  if (i < OHW) {
    const float* prow = plane + (g * OHW + i) * OHW;
    float* obase = out + ((size_t)g * 16) * (OHW * OHW) + i * OHW;
    #pragma unroll
    for (int T = 0; T < 8; ++T) {
      int j = T * 16 + n;
      if (j < OHW) {
        float sc = 0.01f * rsqrtf(prow[j] + shift);
        #pragma unroll
        for (int r = 0; r < 4; ++r) {
          int oc = q * 4 + r;
          obase[(size_t)oc * (OHW * OHW) + j] = acc[T][r] * sc;
        }
      }
    }
  }
}

// ---------------------------------------------------------------------------
extern "C" void kernel_launch(void* const* d_in, const int* in_sizes, int n_in,
                              void* d_out, int out_size, void* d_ws, size_t ws_size,
                              hipStream_t stream) {
  const float* x  = (const float*)d_in[0];
  const float* z  = (const float*)d_in[1];
  const float* fc = (const float*)d_in[2];
  float* out = (float*)d_out;

  char* ws = (char*)d_ws;
  unsigned short* Wp = (unsigned short*)(ws);        // 2 MB (16*64*8*16*8 bf16)
  float*  Mt     = (float*)(ws + 2097152);           // 16 KB
  float*  S      = (float*)(ws + 2113536);           // 4 MB
  float*  plane  = (float*)(ws + 6307840);           // 1 MB
  double* red    = (double*)(ws + 7307840);          // 16 B
  float*  shiftp = (float*)(ws + 7307856);           // 4 B

  fft_mat_kernel<<<16, 256, 0, stream>>>(fc, Mt);
  weight_kernel<<<1024, 256, 0, stream>>>(z, Mt, Wp);
  sq_sum_kernel<<<(16 * 65536) / 256, 256, 0, stream>>>(x, S, red);
  box_kernel<<<(16 * OHW * OHW + 255) / 256, 256, 0, stream>>>(S, plane, red);
  finalize_kernel<<<1, 1, 0, stream>>>(red, shiftp);
  conv_mfma_kernel<<<dim3(32, 16), 256, 0, stream>>>(x, Wp, plane, shiftp, out);
}

// Round 3
// 496.793 us; speedup vs baseline: 3.2246x; 1.4542x over previous
//
#include <hip/hip_runtime.h>

typedef short short8 __attribute__((ext_vector_type(8)));
typedef float f32x4 __attribute__((ext_vector_type(4)));
typedef unsigned int uint4v __attribute__((ext_vector_type(4)));

static constexpr int OHW = 125;

__device__ inline unsigned int bf16_rne(float f) {
  unsigned int u = __float_as_uint(f);
  return (u + 0x7FFFu + ((u >> 16) & 1u)) >> 16;
}

// ---------------------------------------------------------------------------
// Kernel 1: build the 64x64 linear filter matrix Mt from freq_coeff.
__global__ __launch_bounds__(256) void fft_mat_kernel(
    const float* __restrict__ fc, float* __restrict__ Mt) {
  int e = blockIdx.x * 256 + threadIdx.x;  // 0..4095
  int uv = e >> 6, xy = e & 63;
  int u = uv >> 3, v = uv & 7, xx = xy >> 3, yy = xy & 7;
  const float R2 = 0.70710678118654752f;
  const float ct[8] = {1.f, R2, 0.f, -R2, -1.f, -R2, 0.f, R2};
  const float st[8] = {0.f, R2, 1.f, R2, 0.f, -R2, -1.f, -R2};
  float sumv = 0.f;
  #pragma unroll
  for (int p = 0; p < 8; ++p) {
    #pragma unroll
    for (int q = 0; q < 8; ++q) {
      float Re, Im;
      if (q <= 4) {
        int th = (p * u + q * v) & 7;
        float a = fc[(p * 5 + q) * 2 + 0];
        float b = fc[(p * 5 + q) * 2 + 1];
        Re = a * ct[th];
        Im = -b * st[th];
      } else {
        int pp = (8 - p) & 7, qq = 8 - q;
        int th = (pp * u + qq * v) & 7;
        float a = fc[(pp * 5 + qq) * 2 + 0];
        float b = fc[(pp * 5 + qq) * 2 + 1];
        Re = a * ct[th];
        Im = b * st[th];   // conjugated
      }
      int ph = (p * xx + q * yy) & 7;
      sumv += Re * ct[ph] - Im * st[ph];
    }
  }
  Mt[e] = sumv * (1.0f / 64.0f);
}

// ---------------------------------------------------------------------------
// Kernel 2: apply filter to z blocks -> bf16 Wq[g][c][oc][kh*8+kw]
__global__ __launch_bounds__(256) void weight_kernel(
    const float* __restrict__ z, const float* __restrict__ Mt,
    unsigned short* __restrict__ Wq) {
  int blk = blockIdx.x;              // 1024 = G*4 + cq
  int G = blk >> 2, cq = blk & 3;
  int b = G >> 4, n1 = (G >> 2) & 3, n2 = G & 3;
  int oc = G & 15;
  int tid = threadIdx.x;
  int cs = tid >> 6, xy = tid & 63;
  __shared__ float Ms[4096];
  __shared__ float zb[4][64];
  for (int i = tid; i < 4096; i += 256) Ms[i] = Mt[i];
  for (int it = 0; it < 4; ++it) {
    int c = cq * 16 + cs * 4 + it;
    __syncthreads();
    int u = xy >> 3, vv = xy & 7;
    zb[cs][xy] = z[(size_t)(b * 64 + c) * 1024 + (n1 * 8 + u) * 32 + (n2 * 8 + vv)];
    __syncthreads();
    float acc = 0.f;
    #pragma unroll
    for (int i = 0; i < 64; ++i) acc += Ms[i * 64 + xy] * zb[cs][i];
    Wq[((size_t)(b * 64 + c) * 16 + oc) * 64 + xy] = (unsigned short)bf16_rne(acc);
  }
}

// ---------------------------------------------------------------------------
// Kernel 3: S[g][h][w] = sum_c x[g*64+c][h][w]^2 (float4); zero reduction acc
__global__ __launch_bounds__(256) void sq_sum_kernel(
    const float* __restrict__ x, float* __restrict__ S, double* __restrict__ red) {
  if (blockIdx.x == 0 && threadIdx.x < 2) red[threadIdx.x] = 0.0;
  int idx = blockIdx.x * 256 + threadIdx.x;  // 16 * 16384 float4s
  int g = idx >> 14, p4 = idx & 16383;
  const f32x4* xp = (const f32x4*)(x + (size_t)g * 64 * 65536) + p4;
  f32x4 s = {0.f, 0.f, 0.f, 0.f};
  #pragma unroll 8
  for (int c = 0; c < 64; ++c) {
    f32x4 v = xp[(size_t)c * 16384];
    s += v * v;
  }
  ((f32x4*)S)[idx] = s;
}

// ---------------------------------------------------------------------------
// Kernel 4: plane = 8x8 stride-2 box over S ; reduce sum/sumsq (f64)
__global__ __launch_bounds__(256) void box_kernel(
    const float* __restrict__ S, float* __restrict__ plane, double* __restrict__ red) {
  int idx = blockIdx.x * 256 + threadIdx.x;
  double v = 0.0, v2 = 0.0;
  if (idx < 16 * OHW * OHW) {
    int g = idx / (OHW * OHW);
    int rem = idx - g * (OHW * OHW);
    int i = rem / OHW, j = rem - (rem / OHW) * OHW;
    const float* Sp = S + (size_t)g * 65536 + (2 * i) * 256 + 2 * j;
    float s = 0.f;
    #pragma unroll
    for (int r = 0; r < 8; ++r)
      #pragma unroll
      for (int cc = 0; cc < 8; ++cc) s += Sp[r * 256 + cc];
    plane[idx] = s;
    v = (double)s;
    v2 = (double)s * (double)s;
  }
  #pragma unroll
  for (int off = 32; off > 0; off >>= 1) {
    v += __shfl_down(v, off);
    v2 += __shfl_down(v2, off);
  }
  __shared__ double sv[4], sv2[4];
  int wid = threadIdx.x >> 6, lane = threadIdx.x & 63;
  if (lane == 0) { sv[wid] = v; sv2[wid] = v2; }
  __syncthreads();
  if (threadIdx.x == 0) {
    atomicAdd(&red[0], sv[0] + sv[1] + sv[2] + sv[3]);
    atomicAdd(&red[1], sv2[0] + sv2[1] + sv2[2] + sv2[3]);
  }
}

// ---------------------------------------------------------------------------
// Kernel 5: shift = std(norm_full, ddof=1)/10 + 1e-9 (x16 replication folded)
__global__ void finalize_kernel(const double* __restrict__ red, float* __restrict__ shiftp) {
  double sum = red[0], sumsq = red[1];
  double n = 256.0 * OHW * OHW;
  double mu = 16.0 * sum / n;
  double var = (16.0 * sumsq - n * mu * mu) / (n - 1.0);
  *shiftp = (float)(sqrt(var) / 10.0 + 1e-9);
}

// ---------------------------------------------------------------------------
// Kernel 6: MFMA implicit-GEMM grouped conv + scaling, v2.
// Grid (g=16 fast, iblk=32, jh=2). Block: 4 output rows i0..i0+3, 64 j (jh half).
// K order (c, kh, kw): B frag = 8 consecutive x cols of one row -> row-major
// bf16 LDS tile (14 rows x pitch 144 bf16 = 72 dwords, no replication).
// A frags (weights) read straight from global (L1-resident, 2KB per (g,c)).
// Double-buffered LDS (2 x 1008 dwords), one barrier per c, x & A prefetched.
__global__ __launch_bounds__(256) void conv_mfma2_kernel(
    const float* __restrict__ x, const unsigned short* __restrict__ Wq,
    const float* __restrict__ plane, const float* __restrict__ shiftp,
    float* __restrict__ out) {
  __shared__ unsigned int ldsx[2016];
  const int g = blockIdx.x, iblk = blockIdx.y, jh = blockIdx.z;
  const int i0 = iblk * 4;
  const int tid = threadIdx.x;
  const int lane = tid & 63, ri = tid >> 6;
  const int q = lane >> 4, n = lane & 15;

  const float* xg = x + (size_t)g * 64 * 65536;
  const unsigned short* wgc = Wq + (size_t)g * 65536;

  // staging geometry: 14 rows x 36 float4 (cols 128*jh .. +143, clamped)
  int it_goff[2], it_l[2];
  bool it_act[2];
  #pragma unroll
  for (int s = 0; s < 2; ++s) {
    int item = tid + (s << 8);
    int row = item / 36, c4 = item - row * 36;
    it_act[s] = row < 14;
    int rabs = 2 * i0 + row; if (rabs > 255) rabs = 255;
    int cabs = 128 * jh + 4 * c4; if (cabs > 252) cabs = 252;
    it_goff[s] = rabs * 256 + cabs;
    it_l[s] = row * 72 + 2 * c4;
  }
  const int aoff0 = n * 64 + q * 8;       // (oc=n)*64 + kh(=q)*8
  int dbase[2];
  #pragma unroll
  for (int h = 0; h < 2; ++h)
    dbase[h] = (2 * ri + q + 4 * h) * 72 + n;

  f32x4 acc[4];
  #pragma unroll
  for (int t = 0; t < 4; ++t) acc[t] = (f32x4){0.f, 0.f, 0.f, 0.f};

  f32x4 xv[2];
  short8 a_cur[2], a_nxt[2];

  // preload c=0 x + A, store x(0) into buf0
  #pragma unroll
  for (int s = 0; s < 2; ++s) xv[s] = *(const f32x4*)(xg + it_goff[s]);
  #pragma unroll
  for (int h = 0; h < 2; ++h)
    a_cur[h] = *(const short8*)(wgc + aoff0 + 32 * h);
  #pragma unroll
  for (int s = 0; s < 2; ++s) {
    if (it_act[s]) {
      unsigned int p0 = bf16_rne(xv[s][0]) | (bf16_rne(xv[s][1]) << 16);
      unsigned int p1 = bf16_rne(xv[s][2]) | (bf16_rne(xv[s][3]) << 16);
      ldsx[it_l[s]] = p0;
      ldsx[it_l[s] + 1] = p1;
    }
  }
  // preload c=1
  #pragma unroll
  for (int s = 0; s < 2; ++s) xv[s] = *(const f32x4*)(xg + 65536 + it_goff[s]);
  #pragma unroll
  for (int h = 0; h < 2; ++h)
    a_nxt[h] = *(const short8*)(wgc + 1024 + aoff0 + 32 * h);
  __syncthreads();

  for (int c = 0; c < 64; ++c) {
    int cb = c & 1;
    if (c < 63) {
      int bo = ((c + 1) & 1) * 1008;
      #pragma unroll
      for (int s = 0; s < 2; ++s) {
        if (it_act[s]) {
          unsigned int p0 = bf16_rne(xv[s][0]) | (bf16_rne(xv[s][1]) << 16);
          unsigned int p1 = bf16_rne(xv[s][2]) | (bf16_rne(xv[s][3]) << 16);
          ldsx[bo + it_l[s]] = p0;
          ldsx[bo + it_l[s] + 1] = p1;
        }
      }
      if (c < 62) {
        const float* xc = xg + (size_t)(c + 2) * 65536;
        #pragma unroll
        for (int s = 0; s < 2; ++s) xv[s] = *(const f32x4*)(xc + it_goff[s]);
      }
    }
    // compute c from buf cb
    const unsigned int* xb = ldsx + cb * 1008;
    #pragma unroll
    for (int h = 0; h < 2; ++h) {
      short8 af = a_cur[h];
      int base = dbase[h];
      #pragma unroll
      for (int T = 0; T < 4; ++T) {
        int d = base + 16 * T;
        uint4v u;
        u.x = xb[d]; u.y = xb[d + 1]; u.z = xb[d + 2]; u.w = xb[d + 3];
        short8 bf = __builtin_bit_cast(short8, u);
        acc[T] = __builtin_amdgcn_mfma_f32_16x16x32_bf16(af, bf, acc[T], 0, 0, 0);
      }
    }
    a_cur[0] = a_nxt[0];
    a_cur[1] = a_nxt[1];
    if (c < 62) {
      const unsigned short* wc = wgc + (size_t)(c + 2) * 1024;
      #pragma unroll
      for (int h = 0; h < 2; ++h)
        a_nxt[h] = *(const short8*)(wc + aoff0 + 32 * h);
    }
    __syncthreads();
  }

  float shift = *shiftp;
  int i = i0 + ri;
  if (i < OHW) {
    const float* prow = plane + (g * OHW + i) * OHW;
    float* obase = out + (size_t)g * 16 * (OHW * OHW) + i * OHW;
    #pragma unroll
    for (int T = 0; T < 4; ++T) {
      int j = jh * 64 + T * 16 + n;
      if (j < OHW) {
        float sc = 0.01f * rsqrtf(prow[j] + shift);
        #pragma unroll
        for (int r = 0; r < 4; ++r) {
          int oc = q * 4 + r;
          obase[(size_t)oc * (OHW * OHW) + j] = acc[T][r] * sc;
        }
      }
    }
  }
}

// ---------------------------------------------------------------------------
extern "C" void kernel_launch(void* const* d_in, const int* in_sizes, int n_in,
                              void* d_out, int out_size, void* d_ws, size_t ws_size,
                              hipStream_t stream) {
  const float* x  = (const float*)d_in[0];
  const float* z  = (const float*)d_in[1];
  const float* fc = (const float*)d_in[2];
  float* out = (float*)d_out;

  char* ws = (char*)d_ws;
  unsigned short* Wq = (unsigned short*)(ws);        // 2 MB (16*64*16*64 bf16)
  float*  Mt     = (float*)(ws + 2097152);           // 16 KB
  float*  S      = (float*)(ws + 2113536);           // 4 MB
  float*  plane  = (float*)(ws + 6307840);           // 1 MB
  double* red    = (double*)(ws + 7307840);          // 16 B
  float*  shiftp = (float*)(ws + 7307856);           // 4 B

  fft_mat_kernel<<<16, 256, 0, stream>>>(fc, Mt);
  weight_kernel<<<1024, 256, 0, stream>>>(z, Mt, Wq);
  sq_sum_kernel<<<1024, 256, 0, stream>>>(x, S, red);
  box_kernel<<<(16 * OHW * OHW + 255) / 256, 256, 0, stream>>>(S, plane, red);
  finalize_kernel<<<1, 1, 0, stream>>>(red, shiftp);
  conv_mfma2_kernel<<<dim3(16, 32, 2), 256, 0, stream>>>(x, Wq, plane, shiftp, out);
}

// Round 4
// 408.864 us; speedup vs baseline: 3.9180x; 1.2151x over previous
//
#include <hip/hip_runtime.h>

typedef short short8 __attribute__((ext_vector_type(8)));
typedef float f32x4 __attribute__((ext_vector_type(4)));
typedef unsigned int uint4v __attribute__((ext_vector_type(4)));

static constexpr int OHW = 125;
static constexpr int PLN = OHW * OHW;   // 15625

__device__ inline unsigned int bf16_rne(float f) {
  unsigned int u = __float_as_uint(f);
  return (u + 0x7FFFu + ((u >> 16) & 1u)) >> 16;
}

// ---------------------------------------------------------------------------
// Kernel 1: build the 64x64 linear filter matrix Mt from freq_coeff.
// Also zeroes the fp64 reduction accumulator used by conv_fused.
__global__ __launch_bounds__(256) void fft_mat_kernel(
    const float* __restrict__ fc, float* __restrict__ Mt, double* __restrict__ red) {
  if (blockIdx.x == 0 && threadIdx.x < 2) red[threadIdx.x] = 0.0;
  int e = blockIdx.x * 256 + threadIdx.x;  // 0..4095
  int uv = e >> 6, xy = e & 63;
  int u = uv >> 3, v = uv & 7, xx = xy >> 3, yy = xy & 7;
  const float R2 = 0.70710678118654752f;
  const float ct[8] = {1.f, R2, 0.f, -R2, -1.f, -R2, 0.f, R2};
  const float st[8] = {0.f, R2, 1.f, R2, 0.f, -R2, -1.f, -R2};
  float sumv = 0.f;
  #pragma unroll
  for (int p = 0; p < 8; ++p) {
    #pragma unroll
    for (int q = 0; q < 8; ++q) {
      float Re, Im;
      if (q <= 4) {
        int th = (p * u + q * v) & 7;
        float a = fc[(p * 5 + q) * 2 + 0];
        float b = fc[(p * 5 + q) * 2 + 1];
        Re = a * ct[th];
        Im = -b * st[th];
      } else {
        int pp = (8 - p) & 7, qq = 8 - q;
        int th = (pp * u + qq * v) & 7;
        float a = fc[(pp * 5 + qq) * 2 + 0];
        float b = fc[(pp * 5 + qq) * 2 + 1];
        Re = a * ct[th];
        Im = b * st[th];   // conjugated
      }
      int ph = (p * xx + q * yy) & 7;
      sumv += Re * ct[ph] - Im * st[ph];
    }
  }
  Mt[e] = sumv * (1.0f / 64.0f);
}

// ---------------------------------------------------------------------------
// Kernel 2: apply filter to z blocks -> bf16 Wq[g][c][oc][kh*8+kw]
__global__ __launch_bounds__(256) void weight_kernel(
    const float* __restrict__ z, const float* __restrict__ Mt,
    unsigned short* __restrict__ Wq) {
  int blk = blockIdx.x;              // 1024 = G*4 + cq
  int G = blk >> 2, cq = blk & 3;
  int b = G >> 4, n1 = (G >> 2) & 3, n2 = G & 3;
  int oc = G & 15;
  int tid = threadIdx.x;
  int cs = tid >> 6, xy = tid & 63;
  __shared__ float Ms[4096];
  __shared__ float zb[4][64];
  for (int i = tid; i < 4096; i += 256) Ms[i] = Mt[i];
  for (int it = 0; it < 4; ++it) {
    int c = cq * 16 + cs * 4 + it;
    __syncthreads();
    int u = xy >> 3, vv = xy & 7;
    zb[cs][xy] = z[(size_t)(b * 64 + c) * 1024 + (n1 * 8 + u) * 32 + (n2 * 8 + vv)];
    __syncthreads();
    float acc = 0.f;
    #pragma unroll
    for (int i = 0; i < 64; ++i) acc += Ms[i * 64 + xy] * zb[cs][i];
    Wq[((size_t)(b * 64 + c) * 16 + oc) * 64 + xy] = (unsigned short)bf16_rne(acc);
  }
}

// ---------------------------------------------------------------------------
// Kernel 3: fused MFMA conv + norm-plane computation.
// Grid (g=16 fast, iblk=32, jh=2). Per block: 4 output rows, 64 j.
// K order (c, kh, kw). x staged fp32->bf16 into double-buffered LDS; weights
// read straight from global. While staging, each thread accumulates fp32
// column-pair sums of x^2 (exact fp32, pre-rounding) into registers; at block
// end the 8x8 stride-2 window sums are assembled once from LDS and written to
// plane[] + fp64 sum/sumsq atomics for the global std. resp written unscaled.
__global__ __launch_bounds__(256) void conv_fused_kernel(
    const float* __restrict__ x, const unsigned short* __restrict__ Wq,
    float* __restrict__ resp, float* __restrict__ plane, double* __restrict__ red) {
  __shared__ unsigned int ldsx[2016];
  const int g = blockIdx.x, iblk = blockIdx.y, jh = blockIdx.z;
  const int i0 = iblk * 4;
  const int tid = threadIdx.x;
  const int lane = tid & 63, ri = tid >> 6;
  const int q = lane >> 4, n = lane & 15;

  const float* xg = x + (size_t)g * 64 * 65536;
  const unsigned short* wgc = Wq + (size_t)g * 65536;

  // staging geometry: 14 rows x 36 float4 (cols 128*jh .. +143, clamped)
  int it_goff[2], it_l[2];
  bool it_act[2];
  #pragma unroll
  for (int s = 0; s < 2; ++s) {
    int item = tid + (s << 8);
    int row = item / 36, c4 = item - row * 36;
    it_act[s] = row < 14;
    int rabs = 2 * i0 + row; if (rabs > 255) rabs = 255;
    int cabs = 128 * jh + 4 * c4; if (cabs > 252) cabs = 252;
    it_goff[s] = rabs * 256 + cabs;
    it_l[s] = row * 72 + 2 * c4;
  }
  const int aoff0 = n * 64 + q * 8;       // (oc=n)*64 + kh(=q)*8
  int dbase[2];
  #pragma unroll
  for (int h = 0; h < 2; ++h)
    dbase[h] = (2 * ri + q + 4 * h) * 72 + n;

  f32x4 acc[4];
  #pragma unroll
  for (int t = 0; t < 4; ++t) acc[t] = (f32x4){0.f, 0.f, 0.f, 0.f};
  float racc[2][2] = {{0.f, 0.f}, {0.f, 0.f}};

  f32x4 xv[2];
  short8 a_cur[2], a_nxt[2];

  // preload c=0 x + A, store x(0) into buf0 (+ accumulate squares)
  #pragma unroll
  for (int s = 0; s < 2; ++s) xv[s] = *(const f32x4*)(xg + it_goff[s]);
  #pragma unroll
  for (int h = 0; h < 2; ++h)
    a_cur[h] = *(const short8*)(wgc + aoff0 + 32 * h);
  #pragma unroll
  for (int s = 0; s < 2; ++s) {
    if (it_act[s]) {
      racc[s][0] += xv[s][0] * xv[s][0] + xv[s][1] * xv[s][1];
      racc[s][1] += xv[s][2] * xv[s][2] + xv[s][3] * xv[s][3];
      unsigned int p0 = bf16_rne(xv[s][0]) | (bf16_rne(xv[s][1]) << 16);
      unsigned int p1 = bf16_rne(xv[s][2]) | (bf16_rne(xv[s][3]) << 16);
      ldsx[it_l[s]] = p0;
      ldsx[it_l[s] + 1] = p1;
    }
  }
  // preload c=1
  #pragma unroll
  for (int s = 0; s < 2; ++s) xv[s] = *(const f32x4*)(xg + 65536 + it_goff[s]);
  #pragma unroll
  for (int h = 0; h < 2; ++h)
    a_nxt[h] = *(const short8*)(wgc + 1024 + aoff0 + 32 * h);
  __syncthreads();

  for (int c = 0; c < 64; ++c) {
    int cb = c & 1;
    if (c < 63) {
      int bo = ((c + 1) & 1) * 1008;
      #pragma unroll
      for (int s = 0; s < 2; ++s) {
        if (it_act[s]) {
          racc[s][0] += xv[s][0] * xv[s][0] + xv[s][1] * xv[s][1];
          racc[s][1] += xv[s][2] * xv[s][2] + xv[s][3] * xv[s][3];
          unsigned int p0 = bf16_rne(xv[s][0]) | (bf16_rne(xv[s][1]) << 16);
          unsigned int p1 = bf16_rne(xv[s][2]) | (bf16_rne(xv[s][3]) << 16);
          ldsx[bo + it_l[s]] = p0;
          ldsx[bo + it_l[s] + 1] = p1;
        }
      }
      if (c < 62) {
        const float* xc = xg + (size_t)(c + 2) * 65536;
        #pragma unroll
        for (int s = 0; s < 2; ++s) xv[s] = *(const f32x4*)(xc + it_goff[s]);
      }
    }
    // compute c from buf cb
    const unsigned int* xb = ldsx + cb * 1008;
    #pragma unroll
    for (int h = 0; h < 2; ++h) {
      short8 af = a_cur[h];
      int base = dbase[h];
      #pragma unroll
      for (int T = 0; T < 4; ++T) {
        int d = base + 16 * T;
        uint4v u;
        u.x = xb[d]; u.y = xb[d + 1]; u.z = xb[d + 2]; u.w = xb[d + 3];
        short8 bf = __builtin_bit_cast(short8, u);
        acc[T] = __builtin_amdgcn_mfma_f32_16x16x32_bf16(af, bf, acc[T], 0, 0, 0);
      }
    }
    a_cur[0] = a_nxt[0];
    a_cur[1] = a_nxt[1];
    if (c < 62) {
      const unsigned short* wc = wgc + (size_t)(c + 2) * 1024;
      #pragma unroll
      for (int h = 0; h < 2; ++h)
        a_nxt[h] = *(const short8*)(wc + aoff0 + 32 * h);
    }
    __syncthreads();
  }

  // ---- resp store (unscaled) ----
  const int i = i0 + ri;
  if (i < OHW) {
    float* rbase = resp + (size_t)g * 16 * PLN + i * OHW;
    #pragma unroll
    for (int T = 0; T < 4; ++T) {
      int j = jh * 64 + T * 16 + n;
      if (j < OHW) {
        #pragma unroll
        for (int r = 0; r < 4; ++r) {
          int oc = q * 4 + r;
          rbase[(size_t)oc * PLN + j] = acc[T][r];
        }
      }
    }
  }

  // ---- norm plane: R (14 x 72 colpair sums) -> 8-row x 4-pair window sums ----
  float* Rl = (float*)ldsx;   // loop ended with __syncthreads(); LDS reusable
  #pragma unroll
  for (int s = 0; s < 2; ++s) {
    if (it_act[s]) {
      Rl[it_l[s]] = racc[s][0];
      Rl[it_l[s] + 1] = racc[s][1];
    }
  }
  __syncthreads();

  int jl = lane;               // 0..63
  float nv = 0.f;
  #pragma unroll
  for (int r = 0; r < 8; ++r) {
    const float* Rr = Rl + (2 * ri + r) * 72 + jl;
    nv += Rr[0] + Rr[1] + Rr[2] + Rr[3];
  }
  int jj = jh * 64 + jl;
  double sv = 0.0, sv2 = 0.0;
  if (i < OHW && jj < OHW) {
    plane[(g * OHW + i) * OHW + jj] = nv;
    sv = (double)nv;
    sv2 = (double)nv * (double)nv;
  }
  #pragma unroll
  for (int off = 32; off > 0; off >>= 1) {
    sv += __shfl_down(sv, off);
    sv2 += __shfl_down(sv2, off);
  }
  __shared__ double sred[8];
  if (lane == 0) { sred[ri] = sv; sred[4 + ri] = sv2; }
  __syncthreads();
  if (tid == 0)
    atomicAdd(&red[0], sred[0] + sred[1] + sred[2] + sred[3]);
  if (tid == 64)
    atomicAdd(&red[1], sred[4] + sred[5] + sred[6] + sred[7]);
}

// ---------------------------------------------------------------------------
// Kernel 4: shift = std(norm_full, ddof=1)/10 + 1e-9 (x16 replication folded)
__global__ void finalize_kernel(const double* __restrict__ red, float* __restrict__ shiftp) {
  double sum = red[0], sumsq = red[1];
  double n = 256.0 * OHW * OHW;
  double mu = 16.0 * sum / n;
  double var = (16.0 * sumsq - n * mu * mu) / (n - 1.0);
  *shiftp = (float)(sqrt(var) / 10.0 + 1e-9);
}

// ---------------------------------------------------------------------------
// Kernel 5: out = resp * 0.01 * rsqrt(plane + shift)
__global__ __launch_bounds__(256) void scale_kernel(
    const float* __restrict__ resp, const float* __restrict__ plane,
    const float* __restrict__ shiftp, float* __restrict__ out) {
  int idx = blockIdx.x * 256 + threadIdx.x;     // 16*16*15625 = 4,000,000
  float shift = *shiftp;
  int gp = idx / (16 * PLN);
  int rem = idx - gp * 16 * PLN;
  int ij = rem % PLN;
  float nv = plane[gp * PLN + ij];
  out[idx] = resp[idx] * 0.01f * rsqrtf(nv + shift);
}

// ---------------------------------------------------------------------------
extern "C" void kernel_launch(void* const* d_in, const int* in_sizes, int n_in,
                              void* d_out, int out_size, void* d_ws, size_t ws_size,
                              hipStream_t stream) {
  const float* x  = (const float*)d_in[0];
  const float* z  = (const float*)d_in[1];
  const float* fc = (const float*)d_in[2];
  float* out = (float*)d_out;

  char* ws = (char*)d_ws;
  unsigned short* Wq = (unsigned short*)(ws);        // 2 MB
  float*  Mt     = (float*)(ws + 2097152);           // 16 KB
  float*  resp   = (float*)(ws + 2113536);           // 16 MB (16*16*15625 f32)
  float*  plane  = (float*)(ws + 18113536);          // 1 MB
  double* red    = (double*)(ws + 19113536);         // 16 B
  float*  shiftp = (float*)(ws + 19113552);          // 4 B

  fft_mat_kernel<<<16, 256, 0, stream>>>(fc, Mt, red);
  weight_kernel<<<1024, 256, 0, stream>>>(z, Mt, Wq);
  conv_fused_kernel<<<dim3(16, 32, 2), 256, 0, stream>>>(x, Wq, resp, plane, red);
  finalize_kernel<<<1, 1, 0, stream>>>(red, shiftp);
  scale_kernel<<<(16 * 16 * PLN) / 256, 256, 0, stream>>>(resp, plane, shiftp, out);
}